// Round 1
// baseline (2932.701 us; speedup 1.0000x reference)
//
#include <hip/hip_runtime.h>

#define DIM 64

// ---------------------------------------------------------------------------
// Degree accumulation: deg_out[src[e]] += 1, deg_in[dst[e]] += 1 (as floats)
// ---------------------------------------------------------------------------
__global__ __launch_bounds__(256) void deg_kernel(
    const int* __restrict__ src, const int* __restrict__ dst,
    float* __restrict__ deg_s, float* __restrict__ deg_d, int E)
{
    int e = blockIdx.x * blockDim.x + threadIdx.x;
    if (e < E) {
        unsafeAtomicAdd(&deg_s[src[e]], 1.0f);
        unsafeAtomicAdd(&deg_d[dst[e]], 1.0f);
    }
}

// d -> d > 0 ? d^-1/2 : 0   (applied to both norm arrays, contiguous)
__global__ __launch_bounds__(256) void norm_kernel(float* __restrict__ d, int n)
{
    int i = blockIdx.x * blockDim.x + threadIdx.x;
    if (i < n) {
        float v = d[i];
        d[i] = (v > 0.0f) ? rsqrtf(v) : 0.0f;
    }
}

// ---------------------------------------------------------------------------
// Fused row-transform + GEMM:  out[row,:] = (in[row,:]*alpha + beta*bprev) @ W
//   has_prev = 0: alpha = ns[row],          beta = 0        (layer 1)
//   has_prev = 1: alpha = ns[row]*nd[row],  beta = ns[row]  (layers 2,3: folds
//                 previous layer's "*norm_dst + b" epilogue into this prologue)
// Block: 256 threads, 16 rows per block. W (64x64) + 16 x-rows staged in LDS.
// ---------------------------------------------------------------------------
__global__ __launch_bounds__(256) void gemm_kernel(
    const float* __restrict__ in, const float* __restrict__ W,
    const float* __restrict__ bprev,
    const float* __restrict__ ns, const float* __restrict__ nd,
    float* __restrict__ out, int has_prev)
{
    __shared__ float Ws[64 * 64];
    __shared__ float xs[16 * 64];
    const int tid = threadIdx.x;
    const int row0 = blockIdx.x * 16;

    // Stage W (4096 floats, 16 per thread, coalesced)
    for (int i = tid; i < 64 * 64; i += 256) Ws[i] = W[i];

    // Stage + transform 16 input rows (1024 floats)
    for (int i = tid; i < 16 * 64; i += 256) {
        int r = i >> 6, c = i & 63;
        int row = row0 + r;
        float s = ns[row];
        float a = has_prev ? s * nd[row] : s;
        float bc = has_prev ? s : 0.0f;
        xs[i] = in[row * 64 + c] * a + bc * bprev[c];
    }
    __syncthreads();

    const int col = tid & 63;
    const int r0 = tid >> 6;   // 0..3; this thread does rows r0, r0+4, r0+8, r0+12
    float acc0 = 0.f, acc1 = 0.f, acc2 = 0.f, acc3 = 0.f;
#pragma unroll
    for (int k = 0; k < 64; ++k) {
        float w = Ws[k * 64 + col];          // 2-way bank alias: free
        acc0 += xs[(r0     ) * 64 + k] * w;  // broadcast within wave: free
        acc1 += xs[(r0 +  4) * 64 + k] * w;
        acc2 += xs[(r0 +  8) * 64 + k] * w;
        acc3 += xs[(r0 + 12) * 64 + k] * w;
    }
    out[(row0 + r0     ) * 64 + col] = acc0;
    out[(row0 + r0 +  4) * 64 + col] = acc1;
    out[(row0 + r0 +  8) * 64 + col] = acc2;
    out[(row0 + r0 + 12) * 64 + col] = acc3;
}

// ---------------------------------------------------------------------------
// Edge scatter-add: agg[dst[e],:] += h[src[e],:]
// 16 lanes per edge, float4 per lane, 4 native f32 atomics per lane.
// ---------------------------------------------------------------------------
__global__ __launch_bounds__(256) void scatter_kernel(
    const float* __restrict__ h, const int* __restrict__ src,
    const int* __restrict__ dst, float* __restrict__ agg, int E)
{
    int gtid = blockIdx.x * blockDim.x + threadIdx.x;
    int lane = gtid & 63;
    int wave = gtid >> 6;
    int e = wave * 4 + (lane >> 4);
    int fo = (lane & 15) * 4;
    if (e < E) {
        int s = src[e], d = dst[e];
        const float4 v = *(const float4*)(h + (size_t)s * 64 + fo);
        float* p = agg + (size_t)d * 64 + fo;
        unsafeAtomicAdd(p + 0, v.x);
        unsafeAtomicAdd(p + 1, v.y);
        unsafeAtomicAdd(p + 2, v.z);
        unsafeAtomicAdd(p + 3, v.w);
    }
}

// out[i] = out[i] * nd[row] + b[col]   (final layer epilogue)
__global__ __launch_bounds__(256) void epilogue_kernel(
    float* __restrict__ out, const float* __restrict__ nd,
    const float* __restrict__ b, int total)
{
    int i = blockIdx.x * blockDim.x + threadIdx.x;
    if (i < total) {
        int row = i >> 6, c = i & 63;
        out[i] = out[i] * nd[row] + b[c];
    }
}

// ---------------------------------------------------------------------------
extern "C" void kernel_launch(void* const* d_in, const int* in_sizes, int n_in,
                              void* d_out, int out_size, void* d_ws, size_t ws_size,
                              hipStream_t stream)
{
    const float* x  = (const float*)d_in[0];
    const float* W1 = (const float*)d_in[1];
    const float* b1 = (const float*)d_in[2];
    const float* W2 = (const float*)d_in[3];
    const float* b2 = (const float*)d_in[4];
    const float* W3 = (const float*)d_in[5];
    const float* b3 = (const float*)d_in[6];
    const int*  src = (const int*)d_in[7];
    const int*  dst = (const int*)d_in[8];

    const int E = in_sizes[7];
    const int N = in_sizes[0] / DIM;

    // ws layout: ns[N] | nd[N] | h[N*64]
    float* ns  = (float*)d_ws;
    float* nd  = ns + N;
    float* h   = nd + N;
    float* agg = (float*)d_out;   // reuse output buffer as the agg accumulator

    const size_t feat_bytes = (size_t)N * DIM * sizeof(float);

    // Norms
    hipMemsetAsync(ns, 0, 2 * (size_t)N * sizeof(float), stream);
    deg_kernel<<<(E + 255) / 256, 256, 0, stream>>>(src, dst, ns, nd, E);
    norm_kernel<<<(2 * N + 255) / 256, 256, 0, stream>>>(ns, 2 * N);

    const int gemm_blocks = N / 16;
    const int scat_blocks = (E + 15) / 16;

    // Layer 1: h = (x * ns) @ W1 ; agg = scatter(h)
    gemm_kernel<<<gemm_blocks, 256, 0, stream>>>(x, W1, b1, ns, nd, h, 0);
    hipMemsetAsync(agg, 0, feat_bytes, stream);
    scatter_kernel<<<scat_blocks, 256, 0, stream>>>(h, src, dst, agg, E);

    // Layer 2: h = ((agg*nd + b1) * ns) @ W2 ; agg = scatter(h)
    gemm_kernel<<<gemm_blocks, 256, 0, stream>>>(agg, W2, b1, ns, nd, h, 1);
    hipMemsetAsync(agg, 0, feat_bytes, stream);
    scatter_kernel<<<scat_blocks, 256, 0, stream>>>(h, src, dst, agg, E);

    // Layer 3: h = ((agg*nd + b2) * ns) @ W3 ; agg = scatter(h)
    gemm_kernel<<<gemm_blocks, 256, 0, stream>>>(agg, W3, b2, ns, nd, h, 1);
    hipMemsetAsync(agg, 0, feat_bytes, stream);
    scatter_kernel<<<scat_blocks, 256, 0, stream>>>(h, src, dst, agg, E);

    // Final epilogue: out = agg * nd + b3
    epilogue_kernel<<<(N * DIM + 255) / 256, 256, 0, stream>>>(agg, nd, b3, N * DIM);
}

// Round 2
// 469.282 us; speedup vs baseline: 6.2493x; 6.2493x over previous
//
#include <hip/hip_runtime.h>

#define DIM 64

// ---------------------------------------------------------------------------
// Integer degree histograms: cs[src[e]]++, cd[dst[e]]++
// ---------------------------------------------------------------------------
__global__ __launch_bounds__(256) void hist_kernel(
    const int* __restrict__ src, const int* __restrict__ dst,
    int* __restrict__ cs, int* __restrict__ cd, int E)
{
    int e = blockIdx.x * blockDim.x + threadIdx.x;
    if (e < E) {
        atomicAdd(&cs[src[e]], 1);
        atomicAdd(&cd[dst[e]], 1);
    }
}

// ns[i] = cs[i]>0 ? cs[i]^-1/2 : 0 ; nd likewise
__global__ __launch_bounds__(256) void norm_kernel(
    const int* __restrict__ cs, const int* __restrict__ cd,
    float* __restrict__ ns, float* __restrict__ nd, int n)
{
    int i = blockIdx.x * blockDim.x + threadIdx.x;
    if (i < n) {
        int a = cs[i], b = cd[i];
        ns[i] = a > 0 ? rsqrtf((float)a) : 0.0f;
        nd[i] = b > 0 ? rsqrtf((float)b) : 0.0f;
    }
}

// ---------------------------------------------------------------------------
// Exclusive scan of cd[N] -> rs[N] (row starts), three tiny kernels.
// scan1: 64 blocks x 1024 elements (256 thr x 4), block-exclusive + bsum
// ---------------------------------------------------------------------------
__global__ __launch_bounds__(256) void scan1_kernel(
    const int* __restrict__ cd, int* __restrict__ rs, int* __restrict__ bsum)
{
    __shared__ int s[256];
    const int t = threadIdx.x;
    const int base = blockIdx.x * 1024 + t * 4;
    int v0 = cd[base], v1 = cd[base + 1], v2 = cd[base + 2], v3 = cd[base + 3];
    int tsum = v0 + v1 + v2 + v3;
    s[t] = tsum;
    __syncthreads();
    // Hillis-Steele inclusive scan over 256 thread sums
    for (int off = 1; off < 256; off <<= 1) {
        int x = (t >= off) ? s[t - off] : 0;
        __syncthreads();
        s[t] += x;
        __syncthreads();
    }
    int excl = s[t] - tsum;
    rs[base]     = excl;
    rs[base + 1] = excl + v0;
    rs[base + 2] = excl + v0 + v1;
    rs[base + 3] = excl + v0 + v1 + v2;
    if (t == 255) bsum[blockIdx.x] = s[255];
}

// scan2: exclusive scan of the 64 block sums (single thread — 64 ints)
__global__ void scan2_kernel(int* __restrict__ bsum, int nb)
{
    if (threadIdx.x == 0 && blockIdx.x == 0) {
        int acc = 0;
        for (int i = 0; i < nb; ++i) { int v = bsum[i]; bsum[i] = acc; acc += v; }
    }
}

// scan3: add block offsets; init cursor = row start
__global__ __launch_bounds__(256) void scan3_kernel(
    int* __restrict__ rs, const int* __restrict__ bsum, int* __restrict__ cur, int n)
{
    int i = blockIdx.x * blockDim.x + threadIdx.x;
    if (i < n) {
        int v = rs[i] + bsum[i >> 10];
        rs[i] = v;
        cur[i] = v;
    }
}

// Fill: ssrc[pos] = src[e] at pos = cur[dst[e]]++  (int atomics, cheap)
// After this, cur[i] == row end for node i.
__global__ __launch_bounds__(256) void fill_kernel(
    const int* __restrict__ src, const int* __restrict__ dst,
    int* __restrict__ cur, int* __restrict__ ssrc, int E)
{
    int e = blockIdx.x * blockDim.x + threadIdx.x;
    if (e < E) {
        int pos = atomicAdd(&cur[dst[e]], 1);
        ssrc[pos] = src[e];
    }
}

// ---------------------------------------------------------------------------
// Gather aggregation: agg[i,:] = sum_{j in [rs[i],cur[i])} h[ssrc[j],:]
// One wave per dst node; lane = feature column. Each agg row written once.
// ---------------------------------------------------------------------------
__global__ __launch_bounds__(256) void gather_agg_kernel(
    const float* __restrict__ h, const int* __restrict__ ssrc,
    const int* __restrict__ rs, const int* __restrict__ cur,
    float* __restrict__ agg, int N)
{
    int wid  = (blockIdx.x * blockDim.x + threadIdx.x) >> 6;
    int lane = threadIdx.x & 63;
    if (wid >= N) return;
    int beg = rs[wid], end = cur[wid];
    float acc = 0.0f;
    int j = beg;
    for (; j + 1 < end; j += 2) {            // 2-edge unroll for MLP
        int s0 = ssrc[j], s1 = ssrc[j + 1];
        float a = h[s0 * 64 + lane];
        float b = h[s1 * 64 + lane];
        acc += a; acc += b;
    }
    if (j < end) acc += h[ssrc[j] * 64 + lane];
    agg[wid * 64 + lane] = acc;
}

// ---------------------------------------------------------------------------
// Fused row-transform + GEMM:  out[row,:] = (in[row,:]*alpha + beta*bprev) @ W
//   has_prev = 0: alpha = ns[row]                       (layer 1)
//   has_prev = 1: alpha = ns[row]*nd[row], beta = ns[row]  (folds prev epilogue)
// ---------------------------------------------------------------------------
__global__ __launch_bounds__(256) void gemm_kernel(
    const float* __restrict__ in, const float* __restrict__ W,
    const float* __restrict__ bprev,
    const float* __restrict__ ns, const float* __restrict__ nd,
    float* __restrict__ out, int has_prev)
{
    __shared__ float Ws[64 * 64];
    __shared__ float xs[16 * 64];
    const int tid = threadIdx.x;
    const int row0 = blockIdx.x * 16;

    for (int i = tid; i < 64 * 64; i += 256) Ws[i] = W[i];

    for (int i = tid; i < 16 * 64; i += 256) {
        int r = i >> 6, c = i & 63;
        int row = row0 + r;
        float s = ns[row];
        float a = has_prev ? s * nd[row] : s;
        float bc = has_prev ? s : 0.0f;
        xs[i] = in[row * 64 + c] * a + bc * bprev[c];
    }
    __syncthreads();

    const int col = tid & 63;
    const int r0 = tid >> 6;
    float acc0 = 0.f, acc1 = 0.f, acc2 = 0.f, acc3 = 0.f;
#pragma unroll
    for (int k = 0; k < 64; ++k) {
        float w = Ws[k * 64 + col];
        acc0 += xs[(r0     ) * 64 + k] * w;
        acc1 += xs[(r0 +  4) * 64 + k] * w;
        acc2 += xs[(r0 +  8) * 64 + k] * w;
        acc3 += xs[(r0 + 12) * 64 + k] * w;
    }
    out[(row0 + r0     ) * 64 + col] = acc0;
    out[(row0 + r0 +  4) * 64 + col] = acc1;
    out[(row0 + r0 +  8) * 64 + col] = acc2;
    out[(row0 + r0 + 12) * 64 + col] = acc3;
}

// out[i] = out[i] * nd[row] + b[col]   (final layer epilogue)
__global__ __launch_bounds__(256) void epilogue_kernel(
    float* __restrict__ out, const float* __restrict__ nd,
    const float* __restrict__ b, int total)
{
    int i = blockIdx.x * blockDim.x + threadIdx.x;
    if (i < total) {
        int row = i >> 6, c = i & 63;
        out[i] = out[i] * nd[row] + b[c];
    }
}

// ---------------------------------------------------------------------------
extern "C" void kernel_launch(void* const* d_in, const int* in_sizes, int n_in,
                              void* d_out, int out_size, void* d_ws, size_t ws_size,
                              hipStream_t stream)
{
    const float* x  = (const float*)d_in[0];
    const float* W1 = (const float*)d_in[1];
    const float* b1 = (const float*)d_in[2];
    const float* W2 = (const float*)d_in[3];
    const float* b2 = (const float*)d_in[4];
    const float* W3 = (const float*)d_in[5];
    const float* b3 = (const float*)d_in[6];
    const int*  src = (const int*)d_in[7];
    const int*  dst = (const int*)d_in[8];

    const int E = in_sizes[7];
    const int N = in_sizes[0] / DIM;

    // ws layout (floats then ints):
    // ns[N] | nd[N] | h[N*64] | cs[N] | cd[N] | rs[N] | cur[N] | bsum[64] | ssrc[E]
    float* ns  = (float*)d_ws;
    float* nd  = ns + N;
    float* h   = nd + N;
    int* cs    = (int*)(h + (size_t)N * DIM);
    int* cd    = cs + N;
    int* rs    = cd + N;
    int* cur   = rs + N;
    int* bsum  = cur + N;
    int* ssrc  = bsum + 64;
    float* agg = (float*)d_out;   // reuse output buffer as the agg buffer

    // ---- CSR build (once) + norms ----
    hipMemsetAsync(cs, 0, 2 * (size_t)N * sizeof(int), stream);   // cs & cd
    hist_kernel<<<(E + 255) / 256, 256, 0, stream>>>(src, dst, cs, cd, E);
    norm_kernel<<<(N + 255) / 256, 256, 0, stream>>>(cs, cd, ns, nd, N);
    scan1_kernel<<<N / 1024, 256, 0, stream>>>(cd, rs, bsum);
    scan2_kernel<<<1, 64, 0, stream>>>(bsum, N / 1024);
    scan3_kernel<<<(N + 255) / 256, 256, 0, stream>>>(rs, bsum, cur, N);
    fill_kernel<<<(E + 255) / 256, 256, 0, stream>>>(src, dst, cur, ssrc, E);

    const int gemm_blocks = N / 16;
    const int agg_blocks  = N / 4;   // one wave per node, 4 waves/block

    // Layer 1
    gemm_kernel<<<gemm_blocks, 256, 0, stream>>>(x, W1, b1, ns, nd, h, 0);
    gather_agg_kernel<<<agg_blocks, 256, 0, stream>>>(h, ssrc, rs, cur, agg, N);
    // Layer 2 (prev epilogue folded into GEMM prologue)
    gemm_kernel<<<gemm_blocks, 256, 0, stream>>>(agg, W2, b1, ns, nd, h, 1);
    gather_agg_kernel<<<agg_blocks, 256, 0, stream>>>(h, ssrc, rs, cur, agg, N);
    // Layer 3
    gemm_kernel<<<gemm_blocks, 256, 0, stream>>>(agg, W3, b2, ns, nd, h, 1);
    gather_agg_kernel<<<agg_blocks, 256, 0, stream>>>(h, ssrc, rs, cur, agg, N);

    // Final epilogue: out = agg * nd + b3
    epilogue_kernel<<<(N * DIM + 255) / 256, 256, 0, stream>>>(agg, nd, b3, N * DIM);
}

// Round 3
// 327.042 us; speedup vs baseline: 8.9673x; 1.4349x over previous
//
#include <hip/hip_runtime.h>

#define DIM 64
#define NG  16          // num graphs (fixed by problem setup)

// ---------------------------------------------------------------------------
// Per-graph CSR build: one 1024-thread block per graph. Edges of graph g are
// [g*epg, (g+1)*epg) and its nodes [g*npg, (g+1)*npg) (fixed problem layout).
// LDS histograms -> norms -> in-block exclusive scan -> rowptr -> LDS-cursor
// fill of ssrc. Zero global atomics.
// ---------------------------------------------------------------------------
__global__ __launch_bounds__(1024) void build_kernel(
    const int* __restrict__ src, const int* __restrict__ dst,
    float* __restrict__ ns, float* __restrict__ nd,
    int* __restrict__ rowptr, int* __restrict__ ssrc,
    int epg, int npg, int N, int E)
{
    __shared__ int hs[4096];
    __shared__ int hd[4096];
    __shared__ int tsum[1024];
    const int g = blockIdx.x;
    const int t = threadIdx.x;
    const int ebase = g * epg;
    const int nbase = g * npg;

    for (int i = t; i < npg; i += 1024) { hs[i] = 0; hd[i] = 0; }
    __syncthreads();

    // histogram (LDS atomics)
    for (int e = t; e < epg; e += 1024) {
        int s = src[ebase + e] - nbase;
        int d = dst[ebase + e] - nbase;
        atomicAdd(&hs[s], 1);
        atomicAdd(&hd[d], 1);
    }
    __syncthreads();

    // norms
    for (int i = t; i < npg; i += 1024) {
        int a = hs[i], b = hd[i];
        ns[nbase + i] = a > 0 ? rsqrtf((float)a) : 0.0f;
        nd[nbase + i] = b > 0 ? rsqrtf((float)b) : 0.0f;
    }

    // exclusive scan of hd (4096 entries, 4 per thread)
    const int b4 = t * 4;
    int v0 = hd[b4], v1 = hd[b4 + 1], v2 = hd[b4 + 2], v3 = hd[b4 + 3];
    int s4 = v0 + v1 + v2 + v3;
    tsum[t] = s4;
    __syncthreads();
    for (int off = 1; off < 1024; off <<= 1) {
        int x = (t >= off) ? tsum[t - off] : 0;
        __syncthreads();
        tsum[t] += x;
        __syncthreads();
    }
    int excl = tsum[t] - s4;

    rowptr[nbase + b4    ] = ebase + excl;
    rowptr[nbase + b4 + 1] = ebase + excl + v0;
    rowptr[nbase + b4 + 2] = ebase + excl + v0 + v1;
    rowptr[nbase + b4 + 3] = ebase + excl + v0 + v1 + v2;
    if (g == gridDim.x - 1 && t == 0) rowptr[N] = E;
    __syncthreads();

    // reuse hd as local cursor
    hd[b4    ] = excl;
    hd[b4 + 1] = excl + v0;
    hd[b4 + 2] = excl + v0 + v1;
    hd[b4 + 3] = excl + v0 + v1 + v2;
    __syncthreads();

    // fill (LDS atomics for positions)
    for (int e = t; e < epg; e += 1024) {
        int s = src[ebase + e];
        int d = dst[ebase + e] - nbase;
        int pos = atomicAdd(&hd[d], 1);
        ssrc[ebase + pos] = s;
    }
}

// ---------------------------------------------------------------------------
// GEMM v2: out[row,:] = (in[row,:]*alpha + beta*bprev) @ W
//   has_prev=0: alpha=ns[row]               (layer 1)
//   has_prev=1: alpha=ns[row]*nd[row], beta=ns[row]  (folds prev epilogue)
// 256 threads, 32 rows/block, 8 outputs/thread (4 rows x 2 cols),
// W transposed in LDS (stride 68: xs reads broadcast-free, W reads 4-way max).
// ---------------------------------------------------------------------------
#define LSTR 68
__global__ __launch_bounds__(256) void gemm_kernel(
    const float* __restrict__ in, const float* __restrict__ W,
    const float* __restrict__ bprev,
    const float* __restrict__ ns, const float* __restrict__ nd,
    float* __restrict__ out, int has_prev)
{
    __shared__ float Wt[64 * LSTR];   // Wt[c][k]
    __shared__ float xs[32 * LSTR];   // xs[r][k]
    const int tid = threadIdx.x;
    const int row0 = blockIdx.x * 32;

    for (int i = tid; i < 64 * 64; i += 256) {
        int k = i >> 6, c = i & 63;
        Wt[c * LSTR + k] = W[i];
    }
    for (int i = tid; i < 32 * 64; i += 256) {
        int r = i >> 6, c = i & 63;
        int row = row0 + r;
        float s = ns[row];
        float a = has_prev ? s * nd[row] : s;
        float bc = has_prev ? s : 0.0f;
        xs[r * LSTR + c] = in[row * 64 + c] * a + bc * bprev[c];
    }
    __syncthreads();

    const int c0 = tid & 31;          // cols c0 and c0+32
    const int r0 = tid >> 5;          // rows r0, r0+8, r0+16, r0+24
    float acc[4][2] = {};
#pragma unroll
    for (int k = 0; k < 64; k += 4) {
        float4 w0 = *(const float4*)&Wt[(c0     ) * LSTR + k];
        float4 w1 = *(const float4*)&Wt[(c0 + 32) * LSTR + k];
#pragma unroll
        for (int rr = 0; rr < 4; ++rr) {
            float4 xv = *(const float4*)&xs[(r0 + 8 * rr) * LSTR + k];
            acc[rr][0] += xv.x * w0.x + xv.y * w0.y + xv.z * w0.z + xv.w * w0.w;
            acc[rr][1] += xv.x * w1.x + xv.y * w1.y + xv.z * w1.z + xv.w * w1.w;
        }
    }
#pragma unroll
    for (int rr = 0; rr < 4; ++rr) {
        int row = row0 + r0 + 8 * rr;
        out[row * 64 + c0     ] = acc[rr][0];
        out[row * 64 + c0 + 32] = acc[rr][1];
    }
}

// ---------------------------------------------------------------------------
// Gather v2: one wave per dst node; 4 edge-groups of 16 lanes x float4.
// 4 x 256B loads in flight per wave; shuffle-reduce across groups.
// fuse_ep=1: out = acc*nd[node] + b (final layer epilogue fused).
// ---------------------------------------------------------------------------
__global__ __launch_bounds__(256) void gather_kernel(
    const float* __restrict__ h, const int* __restrict__ ssrc,
    const int* __restrict__ rowptr, float* __restrict__ out,
    const float* __restrict__ nd, const float* __restrict__ b,
    int N, int fuse_ep)
{
    int wid  = (blockIdx.x * blockDim.x + threadIdx.x) >> 6;
    int lane = threadIdx.x & 63;
    if (wid >= N) return;
    int beg = rowptr[wid], end = rowptr[wid + 1];
    int grp = lane >> 4;
    int sub = lane & 15;
    float4 acc = {0.f, 0.f, 0.f, 0.f};
    for (int j = beg + grp; j < end; j += 4) {
        int s = ssrc[j];
        const float4 v = *(const float4*)(h + (size_t)s * 64 + sub * 4);
        acc.x += v.x; acc.y += v.y; acc.z += v.z; acc.w += v.w;
    }
#pragma unroll
    for (int off = 32; off >= 16; off >>= 1) {
        acc.x += __shfl_down(acc.x, off, 64);
        acc.y += __shfl_down(acc.y, off, 64);
        acc.z += __shfl_down(acc.z, off, 64);
        acc.w += __shfl_down(acc.w, off, 64);
    }
    if (lane < 16) {
        if (fuse_ep) {
            float n = nd[wid];
            const float4 bv = *(const float4*)(b + lane * 4);
            acc.x = acc.x * n + bv.x;
            acc.y = acc.y * n + bv.y;
            acc.z = acc.z * n + bv.z;
            acc.w = acc.w * n + bv.w;
        }
        *(float4*)(out + (size_t)wid * 64 + lane * 4) = acc;
    }
}

// ---------------------------------------------------------------------------
extern "C" void kernel_launch(void* const* d_in, const int* in_sizes, int n_in,
                              void* d_out, int out_size, void* d_ws, size_t ws_size,
                              hipStream_t stream)
{
    const float* x  = (const float*)d_in[0];
    const float* W1 = (const float*)d_in[1];
    const float* b1 = (const float*)d_in[2];
    const float* W2 = (const float*)d_in[3];
    const float* b2 = (const float*)d_in[4];
    const float* W3 = (const float*)d_in[5];
    const float* b3 = (const float*)d_in[6];
    const int*  src = (const int*)d_in[7];
    const int*  dst = (const int*)d_in[8];

    const int E = in_sizes[7];
    const int N = in_sizes[0] / DIM;
    const int epg = E / NG;
    const int npg = N / NG;

    // ws layout: ns[N] | nd[N] | h[N*64] | rowptr[N+1] | ssrc[E]
    float* ns     = (float*)d_ws;
    float* nd     = ns + N;
    float* h      = nd + N;
    int*   rowptr = (int*)(h + (size_t)N * DIM);
    int*   ssrc   = rowptr + N + 1;
    float* agg    = (float*)d_out;

    build_kernel<<<NG, 1024, 0, stream>>>(src, dst, ns, nd, rowptr, ssrc,
                                          epg, npg, N, E);

    const int gemm_blocks = N / 32;
    const int agg_blocks  = N / 4;    // one wave per node, 4 waves/block

    gemm_kernel<<<gemm_blocks, 256, 0, stream>>>(x, W1, b1, ns, nd, h, 0);
    gather_kernel<<<agg_blocks, 256, 0, stream>>>(h, ssrc, rowptr, agg, nd, b3, N, 0);

    gemm_kernel<<<gemm_blocks, 256, 0, stream>>>(agg, W2, b1, ns, nd, h, 1);
    gather_kernel<<<agg_blocks, 256, 0, stream>>>(h, ssrc, rowptr, agg, nd, b3, N, 0);

    gemm_kernel<<<gemm_blocks, 256, 0, stream>>>(agg, W3, b2, ns, nd, h, 1);
    gather_kernel<<<agg_blocks, 256, 0, stream>>>(h, ssrc, rowptr, agg, nd, b3, N, 1);
}

// Round 4
// 294.344 us; speedup vs baseline: 9.9635x; 1.1111x over previous
//
#include <hip/hip_runtime.h>

#define DIM 64
#define NG  16          // num graphs (fixed by problem setup)
#define CPG 16          // edge chunks per graph
#define NPG 4096        // nodes per graph (fixed)

// ---------------------------------------------------------------------------
// B1: per-chunk LDS sub-histograms (256 blocks = NG*CPG, 4096 edges each).
// No global atomics: each block writes its private 4096-entry hists.
// ---------------------------------------------------------------------------
__global__ __launch_bounds__(256) void b1_hist(
    const int* __restrict__ src, const int* __restrict__ dst,
    int* __restrict__ hsub, int* __restrict__ dsub, int chunk, int npg)
{
    __shared__ int hs[NPG], hd[NPG];
    const int blk = blockIdx.x;
    const int g = blk / CPG;
    const int t = threadIdx.x;
    const int ebase = blk * chunk;     // chunks are graph-major contiguous
    const int nbase = g * npg;
    for (int i = t; i < npg; i += 256) { hs[i] = 0; hd[i] = 0; }
    __syncthreads();
    for (int e = t; e < chunk; e += 256) {
        atomicAdd(&hs[src[ebase + e] - nbase], 1);
        atomicAdd(&hd[dst[ebase + e] - nbase], 1);
    }
    __syncthreads();
    for (int i = t; i < npg; i += 256) {
        hsub[blk * npg + i] = hs[i];
        dsub[blk * npg + i] = hd[i];
    }
}

// ---------------------------------------------------------------------------
// B2: one block per graph. Sum sub-hists -> norms; in-block exclusive scan of
// dst degrees -> rowptr; in-place prefix over chunks -> per-chunk cursor
// starts (dsub[k][i] becomes the absolute ssrc position where chunk k's edges
// into node i begin — stable counting sort).
// ---------------------------------------------------------------------------
__global__ __launch_bounds__(1024) void b2_scan(
    const int* __restrict__ hsub, int* __restrict__ dsub,
    float* __restrict__ ns, float* __restrict__ nd,
    int* __restrict__ rowptr, int epg, int npg, int N, int E)
{
    __shared__ int tsum[1024];
    const int g = blockIdx.x;
    const int t = threadIdx.x;
    const int nbase = g * npg;
    const int ebase = g * epg;
    const int i0 = t * 4;

    int dtot[4];
#pragma unroll
    for (int r = 0; r < 4; ++r) {
        int i = i0 + r;
        int sd = 0, dd = 0;
        for (int k = 0; k < CPG; ++k) {
            sd += hsub[(g * CPG + k) * npg + i];
            dd += dsub[(g * CPG + k) * npg + i];
        }
        dtot[r] = dd;
        ns[nbase + i] = sd > 0 ? rsqrtf((float)sd) : 0.0f;
        nd[nbase + i] = dd > 0 ? rsqrtf((float)dd) : 0.0f;
    }
    int s4 = dtot[0] + dtot[1] + dtot[2] + dtot[3];
    tsum[t] = s4;
    __syncthreads();
    for (int off = 1; off < 1024; off <<= 1) {
        int x = (t >= off) ? tsum[t - off] : 0;
        __syncthreads();
        tsum[t] += x;
        __syncthreads();
    }
    int c = ebase + (tsum[t] - s4);
#pragma unroll
    for (int r = 0; r < 4; ++r) {
        int i = i0 + r;
        rowptr[nbase + i] = c;
        int cc = c;
        for (int k = 0; k < CPG; ++k) {
            int* p = &dsub[(g * CPG + k) * npg + i];
            int old = *p; *p = cc; cc += old;
        }
        c += dtot[r];
    }
    if (g == 0 && t == 0) rowptr[N] = E;
}

// ---------------------------------------------------------------------------
// B3: fill ssrc. LDS cursors init from per-chunk starts; ~1 edge/node/chunk
// so LDS atomic contention is near zero. No global atomics.
// ---------------------------------------------------------------------------
__global__ __launch_bounds__(256) void b3_fill(
    const int* __restrict__ src, const int* __restrict__ dst,
    const int* __restrict__ dsub, int* __restrict__ ssrc, int chunk, int npg)
{
    __shared__ int cur[NPG];
    const int blk = blockIdx.x;
    const int g = blk / CPG;
    const int t = threadIdx.x;
    const int ebase = blk * chunk;
    const int nbase = g * npg;
    for (int i = t; i < npg; i += 256) cur[i] = dsub[blk * npg + i];
    __syncthreads();
    for (int e = t; e < chunk; e += 256) {
        int s = src[ebase + e];
        int d = dst[ebase + e] - nbase;
        int pos = atomicAdd(&cur[d], 1);
        ssrc[pos] = s;
    }
}

// ---------------------------------------------------------------------------
// GEMM: out[row,:] = (in[row,:]*alpha + beta*bprev) @ W
//   has_prev=0: alpha=ns[row]               (layer 1)
//   has_prev=1: alpha=ns[row]*nd[row], beta=ns[row]  (folds prev epilogue)
// ---------------------------------------------------------------------------
#define LSTR 68
__global__ __launch_bounds__(256) void gemm_kernel(
    const float* __restrict__ in, const float* __restrict__ W,
    const float* __restrict__ bprev,
    const float* __restrict__ ns, const float* __restrict__ nd,
    float* __restrict__ out, int has_prev)
{
    __shared__ float Wt[64 * LSTR];   // Wt[c][k]
    __shared__ float xs[32 * LSTR];   // xs[r][k]
    const int tid = threadIdx.x;
    const int row0 = blockIdx.x * 32;

    for (int i = tid; i < 64 * 64; i += 256) {
        int k = i >> 6, c = i & 63;
        Wt[c * LSTR + k] = W[i];
    }
    for (int i = tid; i < 32 * 64; i += 256) {
        int r = i >> 6, c = i & 63;
        int row = row0 + r;
        float s = ns[row];
        float a = has_prev ? s * nd[row] : s;
        float bc = has_prev ? s : 0.0f;
        xs[r * LSTR + c] = in[row * 64 + c] * a + bc * bprev[c];
    }
    __syncthreads();

    const int c0 = tid & 31;
    const int r0 = tid >> 5;
    float acc[4][2] = {};
#pragma unroll
    for (int k = 0; k < 64; k += 4) {
        float4 w0 = *(const float4*)&Wt[(c0     ) * LSTR + k];
        float4 w1 = *(const float4*)&Wt[(c0 + 32) * LSTR + k];
#pragma unroll
        for (int rr = 0; rr < 4; ++rr) {
            float4 xv = *(const float4*)&xs[(r0 + 8 * rr) * LSTR + k];
            acc[rr][0] += xv.x * w0.x + xv.y * w0.y + xv.z * w0.z + xv.w * w0.w;
            acc[rr][1] += xv.x * w1.x + xv.y * w1.y + xv.z * w1.z + xv.w * w1.w;
        }
    }
#pragma unroll
    for (int rr = 0; rr < 4; ++rr) {
        int row = row0 + r0 + 8 * rr;
        out[row * 64 + c0     ] = acc[rr][0];
        out[row * 64 + c0 + 32] = acc[rr][1];
    }
}

// ---------------------------------------------------------------------------
// Gather: one wave per dst node; 4 edge-groups of 16 lanes x float4.
// XCD swizzle (swiz=1): all blocks of graph g -> XCD g%8 so the graph's 1 MB
// h-slice stays L2-resident (dispatch round-robin heuristic; perf-only).
// fuse_ep=1: out = acc*nd[node] + b (final epilogue fused).
// ---------------------------------------------------------------------------
__global__ __launch_bounds__(256) void gather_kernel(
    const float* __restrict__ h, const int* __restrict__ ssrc,
    const int* __restrict__ rowptr, float* __restrict__ out,
    const float* __restrict__ nd, const float* __restrict__ b,
    int N, int fuse_ep, int swiz)
{
    int blk = blockIdx.x;
    if (swiz) {
        int x = blk & 7;            // target XCD
        int j = blk >> 3;           // 0..2047
        int g = x + ((j >> 10) << 3);
        blk = (g << 10) + (j & 1023);
    }
    int wid  = blk * 4 + (threadIdx.x >> 6);
    int lane = threadIdx.x & 63;
    if (wid >= N) return;
    int beg = rowptr[wid], end = rowptr[wid + 1];
    int grp = lane >> 4;
    int sub = lane & 15;
    float4 acc = {0.f, 0.f, 0.f, 0.f};
    for (int j = beg + grp; j < end; j += 4) {
        int s = ssrc[j];
        const float4 v = *(const float4*)(h + (size_t)s * 64 + sub * 4);
        acc.x += v.x; acc.y += v.y; acc.z += v.z; acc.w += v.w;
    }
#pragma unroll
    for (int off = 32; off >= 16; off >>= 1) {
        acc.x += __shfl_down(acc.x, off, 64);
        acc.y += __shfl_down(acc.y, off, 64);
        acc.z += __shfl_down(acc.z, off, 64);
        acc.w += __shfl_down(acc.w, off, 64);
    }
    if (lane < 16) {
        if (fuse_ep) {
            float n = nd[wid];
            const float4 bv = *(const float4*)(b + lane * 4);
            acc.x = acc.x * n + bv.x;
            acc.y = acc.y * n + bv.y;
            acc.z = acc.z * n + bv.z;
            acc.w = acc.w * n + bv.w;
        }
        *(float4*)(out + (size_t)wid * 64 + lane * 4) = acc;
    }
}

// ---------------------------------------------------------------------------
extern "C" void kernel_launch(void* const* d_in, const int* in_sizes, int n_in,
                              void* d_out, int out_size, void* d_ws, size_t ws_size,
                              hipStream_t stream)
{
    const float* x  = (const float*)d_in[0];
    const float* W1 = (const float*)d_in[1];
    const float* b1 = (const float*)d_in[2];
    const float* W2 = (const float*)d_in[3];
    const float* b2 = (const float*)d_in[4];
    const float* W3 = (const float*)d_in[5];
    const float* b3 = (const float*)d_in[6];
    const int*  src = (const int*)d_in[7];
    const int*  dst = (const int*)d_in[8];

    const int E = in_sizes[7];
    const int N = in_sizes[0] / DIM;
    const int epg = E / NG;
    const int npg = N / NG;
    const int chunk = epg / CPG;

    // ws layout: ns[N] | nd[N] | h[N*64] | rowptr[N+1] | ssrc[E]
    // hsub/dsub (4 MB each) alias h: consumed before gemm1 writes h.
    float* ns     = (float*)d_ws;
    float* nd     = ns + N;
    float* h      = nd + N;
    int*   rowptr = (int*)(h + (size_t)N * DIM);
    int*   ssrc   = rowptr + N + 1;
    int*   hsub   = (int*)h;
    int*   dsub   = hsub + (size_t)NG * CPG * npg;
    float* agg    = (float*)d_out;

    b1_hist<<<NG * CPG, 256, 0, stream>>>(src, dst, hsub, dsub, chunk, npg);
    b2_scan<<<NG, 1024, 0, stream>>>(hsub, dsub, ns, nd, rowptr, epg, npg, N, E);
    b3_fill<<<NG * CPG, 256, 0, stream>>>(src, dst, dsub, ssrc, chunk, npg);

    const int gemm_blocks = N / 32;
    const int agg_blocks  = N / 4;
    const int swiz = (N == 65536 && npg == 4096) ? 1 : 0;

    gemm_kernel<<<gemm_blocks, 256, 0, stream>>>(x, W1, b1, ns, nd, h, 0);
    gather_kernel<<<agg_blocks, 256, 0, stream>>>(h, ssrc, rowptr, agg, nd, b3, N, 0, swiz);

    gemm_kernel<<<gemm_blocks, 256, 0, stream>>>(agg, W2, b1, ns, nd, h, 1);
    gather_kernel<<<agg_blocks, 256, 0, stream>>>(h, ssrc, rowptr, agg, nd, b3, N, 0, swiz);

    gemm_kernel<<<gemm_blocks, 256, 0, stream>>>(agg, W3, b2, ns, nd, h, 1);
    gather_kernel<<<agg_blocks, 256, 0, stream>>>(h, ssrc, rowptr, agg, nd, b3, N, 1, swiz);
}

// Round 5
// 273.774 us; speedup vs baseline: 10.7121x; 1.0751x over previous
//
#include <hip/hip_runtime.h>

#define DIM 64
#define NG  16          // num graphs (fixed by problem setup)
#define CPG 8           // edge chunks per graph
#define NPG 4096        // nodes per graph (fixed)

// ---------------------------------------------------------------------------
// B1: per-chunk LDS sub-histograms (NG*CPG blocks). No global atomics.
// ---------------------------------------------------------------------------
__global__ __launch_bounds__(256) void b1_hist(
    const int* __restrict__ src, const int* __restrict__ dst,
    int* __restrict__ hsub, int* __restrict__ dsub, int chunk, int npg)
{
    __shared__ int hs[NPG], hd[NPG];
    const int blk = blockIdx.x;
    const int g = blk / CPG;
    const int t = threadIdx.x;
    const int ebase = blk * chunk;     // chunks are graph-major contiguous
    const int nbase = g * npg;
    for (int i = t; i < npg; i += 256) { hs[i] = 0; hd[i] = 0; }
    __syncthreads();
    for (int e = t; e < chunk; e += 256) {
        atomicAdd(&hs[src[ebase + e] - nbase], 1);
        atomicAdd(&hd[dst[ebase + e] - nbase], 1);
    }
    __syncthreads();
    for (int i = t; i < npg; i += 256) {
        hsub[blk * npg + i] = hs[i];
        dsub[blk * npg + i] = hd[i];
    }
}

// ---------------------------------------------------------------------------
// B2: one block per graph. Sum sub-hists -> norms; in-block exclusive scan of
// dst degrees -> rowptr; in-place prefix over chunks -> per-chunk absolute
// cursor starts (stable counting sort).
// ---------------------------------------------------------------------------
__global__ __launch_bounds__(1024) void b2_scan(
    const int* __restrict__ hsub, int* __restrict__ dsub,
    float* __restrict__ ns, float* __restrict__ nd,
    int* __restrict__ rowptr, int epg, int npg, int N, int E)
{
    __shared__ int tsum[1024];
    const int g = blockIdx.x;
    const int t = threadIdx.x;
    const int nbase = g * npg;
    const int ebase = g * epg;
    const int i0 = t * 4;

    int dtot[4];
#pragma unroll
    for (int r = 0; r < 4; ++r) {
        int i = i0 + r;
        int sd = 0, dd = 0;
        for (int k = 0; k < CPG; ++k) {
            sd += hsub[(g * CPG + k) * npg + i];
            dd += dsub[(g * CPG + k) * npg + i];
        }
        dtot[r] = dd;
        ns[nbase + i] = sd > 0 ? rsqrtf((float)sd) : 0.0f;
        nd[nbase + i] = dd > 0 ? rsqrtf((float)dd) : 0.0f;
    }
    int s4 = dtot[0] + dtot[1] + dtot[2] + dtot[3];
    tsum[t] = s4;
    __syncthreads();
    for (int off = 1; off < 1024; off <<= 1) {
        int x = (t >= off) ? tsum[t - off] : 0;
        __syncthreads();
        tsum[t] += x;
        __syncthreads();
    }
    int c = ebase + (tsum[t] - s4);
#pragma unroll
    for (int r = 0; r < 4; ++r) {
        int i = i0 + r;
        rowptr[nbase + i] = c;
        int cc = c;
        for (int k = 0; k < CPG; ++k) {
            int* p = &dsub[(g * CPG + k) * npg + i];
            int old = *p; *p = cc; cc += old;
        }
        c += dtot[r];
    }
    if (g == 0 && t == 0) rowptr[N] = E;
}

// ---------------------------------------------------------------------------
// B3: fill ssrc. LDS cursors init from per-chunk starts. No global atomics.
// ---------------------------------------------------------------------------
__global__ __launch_bounds__(256) void b3_fill(
    const int* __restrict__ src, const int* __restrict__ dst,
    const int* __restrict__ dsub, int* __restrict__ ssrc, int chunk, int npg)
{
    __shared__ int cur[NPG];
    const int blk = blockIdx.x;
    const int g = blk / CPG;
    const int t = threadIdx.x;
    const int ebase = blk * chunk;
    const int nbase = g * npg;
    for (int i = t; i < npg; i += 256) cur[i] = dsub[blk * npg + i];
    __syncthreads();
    for (int e = t; e < chunk; e += 256) {
        int s = src[ebase + e];
        int d = dst[ebase + e] - nbase;
        int pos = atomicAdd(&cur[d], 1);
        ssrc[pos] = s;
    }
}

// ---------------------------------------------------------------------------
// GEMM: out[row,:] = (in[row,:]*alpha + beta*bprev) @ W
//   has_prev=0: alpha=ns[row]               (layer 1)
//   has_prev=1: alpha=ns[row]*nd[row], beta=ns[row]  (folds prev epilogue)
// swiz=1: XCD-affine remap (graph g -> XCD g%8, matching gather) so h/agg
// rows stay in the same XCD's L2 across the whole layer chain.
// ---------------------------------------------------------------------------
#define LSTR 68
__global__ __launch_bounds__(256) void gemm_kernel(
    const float* __restrict__ in, const float* __restrict__ W,
    const float* __restrict__ bprev,
    const float* __restrict__ ns, const float* __restrict__ nd,
    float* __restrict__ out, int has_prev, int swiz)
{
    __shared__ float Wt[64 * LSTR];   // Wt[c][k]
    __shared__ float xs[32 * LSTR];   // xs[r][k]
    const int tid = threadIdx.x;
    int blk = blockIdx.x;
    if (swiz) {                        // 2048 blocks: 16 graphs x 128
        int x = blk & 7;               // XCD (dispatch round-robin heuristic)
        int j = blk >> 3;              // 0..255
        int g = x + ((j >> 7) << 3);   // graph on XCD g%8
        blk = (g << 7) + (j & 127);
    }
    const int row0 = blk * 32;

    for (int i = tid; i < 64 * 64; i += 256) {
        int k = i >> 6, c = i & 63;
        Wt[c * LSTR + k] = W[i];
    }
    for (int i = tid; i < 32 * 64; i += 256) {
        int r = i >> 6, c = i & 63;
        int row = row0 + r;
        float s = ns[row];
        float a = has_prev ? s * nd[row] : s;
        float bc = has_prev ? s : 0.0f;
        xs[r * LSTR + c] = in[row * 64 + c] * a + bc * bprev[c];
    }
    __syncthreads();

    const int c0 = tid & 31;
    const int r0 = tid >> 5;
    float acc[4][2] = {};
#pragma unroll
    for (int k = 0; k < 64; k += 4) {
        float4 w0 = *(const float4*)&Wt[(c0     ) * LSTR + k];
        float4 w1 = *(const float4*)&Wt[(c0 + 32) * LSTR + k];
#pragma unroll
        for (int rr = 0; rr < 4; ++rr) {
            float4 xv = *(const float4*)&xs[(r0 + 8 * rr) * LSTR + k];
            acc[rr][0] += xv.x * w0.x + xv.y * w0.y + xv.z * w0.z + xv.w * w0.w;
            acc[rr][1] += xv.x * w1.x + xv.y * w1.y + xv.z * w1.z + xv.w * w1.w;
        }
    }
#pragma unroll
    for (int rr = 0; rr < 4; ++rr) {
        int row = row0 + r0 + 8 * rr;
        out[row * 64 + c0     ] = acc[rr][0];
        out[row * 64 + c0 + 32] = acc[rr][1];
    }
}

// ---------------------------------------------------------------------------
// Gather: one wave per dst node; 4 edge-groups of 16 lanes x float4,
// unrolled x2 -> 8 edges in flight per wave. XCD swizzle keeps each graph's
// h slice L2-local. fuse_ep=1: out = acc*nd[node] + b (final epilogue).
// ---------------------------------------------------------------------------
__global__ __launch_bounds__(256) void gather_kernel(
    const float* __restrict__ h, const int* __restrict__ ssrc,
    const int* __restrict__ rowptr, float* __restrict__ out,
    const float* __restrict__ nd, const float* __restrict__ b,
    int N, int fuse_ep, int swiz)
{
    int blk = blockIdx.x;
    if (swiz) {                        // 16384 blocks: 16 graphs x 1024
        int x = blk & 7;
        int j = blk >> 3;
        int g = x + ((j >> 10) << 3);
        blk = (g << 10) + (j & 1023);
    }
    int wid  = blk * 4 + (threadIdx.x >> 6);
    int lane = threadIdx.x & 63;
    if (wid >= N) return;
    int beg = rowptr[wid], end = rowptr[wid + 1];
    int grp = lane >> 4;
    int sub = lane & 15;
    float4 acc = {0.f, 0.f, 0.f, 0.f};
    int j = beg + grp;
    for (; j + 4 < end; j += 8) {       // 2 edges per group in flight
        int s0 = ssrc[j];
        int s1 = ssrc[j + 4];
        const float4 v0 = *(const float4*)(h + (size_t)s0 * 64 + sub * 4);
        const float4 v1 = *(const float4*)(h + (size_t)s1 * 64 + sub * 4);
        acc.x += v0.x + v1.x; acc.y += v0.y + v1.y;
        acc.z += v0.z + v1.z; acc.w += v0.w + v1.w;
    }
    if (j < end) {
        int s = ssrc[j];
        const float4 v = *(const float4*)(h + (size_t)s * 64 + sub * 4);
        acc.x += v.x; acc.y += v.y; acc.z += v.z; acc.w += v.w;
    }
#pragma unroll
    for (int off = 32; off >= 16; off >>= 1) {
        acc.x += __shfl_down(acc.x, off, 64);
        acc.y += __shfl_down(acc.y, off, 64);
        acc.z += __shfl_down(acc.z, off, 64);
        acc.w += __shfl_down(acc.w, off, 64);
    }
    if (lane < 16) {
        if (fuse_ep) {
            float n = nd[wid];
            const float4 bv = *(const float4*)(b + lane * 4);
            acc.x = acc.x * n + bv.x;
            acc.y = acc.y * n + bv.y;
            acc.z = acc.z * n + bv.z;
            acc.w = acc.w * n + bv.w;
        }
        *(float4*)(out + (size_t)wid * 64 + lane * 4) = acc;
    }
}

// ---------------------------------------------------------------------------
extern "C" void kernel_launch(void* const* d_in, const int* in_sizes, int n_in,
                              void* d_out, int out_size, void* d_ws, size_t ws_size,
                              hipStream_t stream)
{
    const float* x  = (const float*)d_in[0];
    const float* W1 = (const float*)d_in[1];
    const float* b1 = (const float*)d_in[2];
    const float* W2 = (const float*)d_in[3];
    const float* b2 = (const float*)d_in[4];
    const float* W3 = (const float*)d_in[5];
    const float* b3 = (const float*)d_in[6];
    const int*  src = (const int*)d_in[7];
    const int*  dst = (const int*)d_in[8];

    const int E = in_sizes[7];
    const int N = in_sizes[0] / DIM;
    const int epg = E / NG;
    const int npg = N / NG;
    const int chunk = epg / CPG;

    // ws layout: ns[N] | nd[N] | h[N*64] | rowptr[N+1] | ssrc[E]
    // hsub/dsub (2 MB each) alias h: consumed before gemm1 writes h.
    float* ns     = (float*)d_ws;
    float* nd     = ns + N;
    float* h      = nd + N;
    int*   rowptr = (int*)(h + (size_t)N * DIM);
    int*   ssrc   = rowptr + N + 1;
    int*   hsub   = (int*)h;
    int*   dsub   = hsub + (size_t)NG * CPG * npg;
    float* agg    = (float*)d_out;

    b1_hist<<<NG * CPG, 256, 0, stream>>>(src, dst, hsub, dsub, chunk, npg);
    b2_scan<<<NG, 1024, 0, stream>>>(hsub, dsub, ns, nd, rowptr, epg, npg, N, E);
    b3_fill<<<NG * CPG, 256, 0, stream>>>(src, dst, dsub, ssrc, chunk, npg);

    const int gemm_blocks = N / 32;
    const int agg_blocks  = N / 4;
    const int swiz = (N == 65536 && npg == 4096) ? 1 : 0;

    gemm_kernel<<<gemm_blocks, 256, 0, stream>>>(x, W1, b1, ns, nd, h, 0, swiz);
    gather_kernel<<<agg_blocks, 256, 0, stream>>>(h, ssrc, rowptr, agg, nd, b3, N, 0, swiz);

    gemm_kernel<<<gemm_blocks, 256, 0, stream>>>(agg, W2, b1, ns, nd, h, 1, swiz);
    gather_kernel<<<agg_blocks, 256, 0, stream>>>(h, ssrc, rowptr, agg, nd, b3, N, 0, swiz);

    gemm_kernel<<<gemm_blocks, 256, 0, stream>>>(agg, W3, b2, ns, nd, h, 1, swiz);
    gather_kernel<<<agg_blocks, 256, 0, stream>>>(h, ssrc, rowptr, agg, nd, b3, N, 1, swiz);
}